// Round 13
// baseline (180.145 us; speedup 1.0000x reference)
//
#include <hip/hip_runtime.h>
#include <hip/hip_bf16.h>
#include <stdint.h>

#define SEQ 2048
#define NB 4
#define NH 12
#define DMODEL 768
#define DK 64
#define NTOK (NB*SEQ)          // 8192
#define QSCALE 0.18033688011f  // 0.125 * log2(e)

#define N_X4   (NTOK*DMODEL/4)          // 1572864
#define N_WQ4  (3*DMODEL*DMODEL/4)      // 442368
#define N_WO4  (DMODEL*DMODEL/4)        // 147456

typedef __bf16 bf16_t;
typedef __attribute__((ext_vector_type(4))) bf16_t bf16x4;
typedef __attribute__((ext_vector_type(8))) bf16_t bf16x8;
typedef __attribute__((ext_vector_type(4))) float f32x4;

typedef __attribute__((address_space(3))) uint32_t lds_u32_t;
typedef const __attribute__((address_space(1))) uint32_t glb_u32_t;

__device__ inline void load_lds16(const void* g, void* l) {
    __builtin_amdgcn_global_load_lds((glb_u32_t*)g, (lds_u32_t*)l, 16, 0, 0);
}

// ---------------- fp32 -> bf16 convert (x, wqkv, wo fused; dst regions contiguous) ----------------
__global__ void cvt_all(const float* __restrict__ x, const float* __restrict__ wq,
                        const float* __restrict__ wo, bf16_t* __restrict__ dst) {
    int i = blockIdx.x * blockDim.x + threadIdx.x;   // grid sized exactly
    const float* src; int off;
    if (i < N_X4)              { src = x;  off = i; }
    else if (i < N_X4 + N_WQ4) { src = wq; off = i - N_X4; }
    else                       { src = wo; off = i - (N_X4 + N_WQ4); }
    float4 v = ((const float4*)src)[off];
    bf16x4 o;
    o[0] = (bf16_t)v.x; o[1] = (bf16_t)v.y; o[2] = (bf16_t)v.z; o[3] = (bf16_t)v.w;
    ((bf16x4*)dst)[i] = o;
}

// =================== QKV GEMM: 128x192 tile, BK=32, dbuf + paired-row XOR-8 LDS layout ===================
// LDS view: As = 64 row-pairs x 64 elems (global rows {r, r+64} as 8x16B slots, slot
// s = (hi*4+ch)^(row'&7)); Bs = 96 row-pairs (rows {r, r+96}). Fragment ds_read_b128 then has
// 128B row-stride (full bank wrap) + XOR start variation -> 2-way conflicts (free; was 8-way,
// 2.94x per m136). Staging dest stays uniform-base + lane*16 (source chunk is permuted).
#define QSTAGE(AS, BS, KB) do { \
    _Pragma("unroll") \
    for (int j = 0; j < 2; j++) { \
        int rp = (w*2 + j)*8 + (lane>>3); \
        int s  = lane & 7; \
        int sp = s ^ (rp & 7); \
        int hi = sp >> 2, ch = sp & 3; \
        load_lds16(Ap_ + (size_t)(mt*128 + hi*64 + rp)*DMODEL + (KB) + ch*8, AS + rp*64 + s*8); \
    } \
    _Pragma("unroll") \
    for (int j = 0; j < 3; j++) { \
        int rp = (w*3 + j)*8 + (lane>>3); \
        int s  = lane & 7; \
        int sp = s ^ (rp & 7); \
        int hi = sp >> 2, ch = sp & 3; \
        load_lds16(Bp_ + (size_t)(nt*192 + hi*96 + rp)*DMODEL + (KB) + ch*8, BS + rp*64 + s*8); \
    } \
} while (0)

#define QCOMPUTE(AS, BS) do { \
    bf16x8 af[4]; \
    _Pragma("unroll") \
    for (int f = 0; f < 4; f++) \
        af[f] = *(const bf16x8*)(AS + (f*16 + lr)*64 + ((wy*4 + lq) ^ (lr & 7))*8); \
    _Pragma("unroll") \
    for (int fn = 0; fn < 6; fn++) { \
        bf16x8 bfr = *(const bf16x8*)(BS + (fn*16 + lr)*64 + ((wx*4 + lq) ^ (lr & 7))*8); \
        _Pragma("unroll") \
        for (int fm = 0; fm < 4; fm++) \
            acc[fm][fn] = __builtin_amdgcn_mfma_f32_16x16x32_bf16(af[fm], bfr, acc[fm][fn], 0, 0, 0); \
    } \
} while (0)

__global__ __launch_bounds__(256, 3) void gemm_qkv(
    const bf16_t* __restrict__ Ap_, const bf16_t* __restrict__ Bp_,
    bf16_t* __restrict__ Qo, bf16_t* __restrict__ Ko, bf16_t* __restrict__ VTo)
{
    __shared__ bf16_t As0[128*32];
    __shared__ bf16_t Bs0[192*32];
    __shared__ bf16_t As1[128*32];
    __shared__ bf16_t Bs1[192*32];
    const int mt = blockIdx.x, nt = blockIdx.y;
    const int tid = threadIdx.x;
    const int w = tid >> 6, lane = tid & 63;
    const int wx = w & 1, wy = w >> 1;
    const int lr = lane & 15, lq = lane >> 4;

    f32x4 acc[4][6] = {};
    QSTAGE(As0, Bs0, 0);
    for (int kb = 0; kb < DMODEL; kb += 64) {
        __syncthreads();
        QSTAGE(As1, Bs1, kb + 32);
        QCOMPUTE(As0, Bs0);
        __syncthreads();
        if (kb + 64 < DMODEL) QSTAGE(As0, Bs0, kb + 64);
        QCOMPUTE(As1, Bs1);
    }

    const int t = nt >> 2;                      // 768 = 4*192: tile never spans Q/K/V
    const int ob = (nt & 3) * 192 + wx * 96;    // col base within 768
    if (t == 2) {
        // V: r=0..3 are s-contiguous -> packed b64 stores
        #pragma unroll
        for (int fm = 0; fm < 4; fm++)
            #pragma unroll
            for (int fn = 0; fn < 6; fn++) {
                int m0 = mt*128 + wy*64 + fm*16 + lq*4;
                int o = ob + fn*16 + lr;
                int b = m0 >> 11, s0 = m0 & 2047;
                int h = o >> 6, dk = o & 63;
                bf16x4 v4;
                #pragma unroll
                for (int r = 0; r < 4; r++) v4[r] = (bf16_t)acc[fm][fn][r];
                *(bf16x4*)(VTo + (size_t)((b*NH + h)*DK + dk)*SEQ + s0) = v4;
            }
    } else {
        #pragma unroll
        for (int fm = 0; fm < 4; fm++)
            #pragma unroll
            for (int fn = 0; fn < 6; fn++)
                #pragma unroll
                for (int r = 0; r < 4; r++) {
                    int m = mt*128 + wy*64 + fm*16 + lq*4 + r;
                    int o = ob + fn*16 + lr;
                    int b = m >> 11, s = m & 2047;
                    int h = o >> 6, dk = o & 63;
                    float v = acc[fm][fn][r];
                    if (t == 0) Qo[(size_t)((b*NH + h)*SEQ + s)*DK + dk] = (bf16_t)(v * QSCALE);
                    else        Ko[(size_t)((b*NH + h)*SEQ + s)*DK + dk] = (bf16_t)v;
                }
    }
}

// ---------------- O projection GEMM: 128x64 tile, paired-row XOR-8 LDS, grid (64,12)=768 ----------------
#define OSTAGE(AS, BS, KB) do { \
    _Pragma("unroll") \
    for (int j = 0; j < 2; j++) { \
        int rp = (w*2 + j)*8 + (lane>>3); \
        int s  = lane & 7; \
        int sp = s ^ (rp & 7); \
        int hi = sp >> 2, ch = sp & 3; \
        load_lds16(Ap_ + (size_t)(mt*128 + hi*64 + rp)*DMODEL + (KB) + ch*8, AS + rp*64 + s*8); \
    } \
    { \
        int rp = w*8 + (lane>>3); \
        int s  = lane & 7; \
        int sp = s ^ (rp & 7); \
        int hi = sp >> 2, ch = sp & 3; \
        load_lds16(Bp_ + (size_t)(nt*64 + hi*32 + rp)*DMODEL + (KB) + ch*8, BS + rp*64 + s*8); \
    } \
} while (0)

#define OCOMPUTE(AS, BS) do { \
    bf16x8 af[4], bfr[2]; \
    _Pragma("unroll") \
    for (int f = 0; f < 4; f++) \
        af[f]  = *(const bf16x8*)(AS + (f*16 + lr)*64 + ((wy*4 + lq) ^ (lr & 7))*8); \
    _Pragma("unroll") \
    for (int f = 0; f < 2; f++) \
        bfr[f] = *(const bf16x8*)(BS + (f*16 + lr)*64 + ((wx*4 + lq) ^ (lr & 7))*8); \
    _Pragma("unroll") \
    for (int fm = 0; fm < 4; fm++) \
        _Pragma("unroll") \
        for (int fn = 0; fn < 2; fn++) \
            acc[fm][fn] = __builtin_amdgcn_mfma_f32_16x16x32_bf16(af[fm], bfr[fn], acc[fm][fn], 0, 0, 0); \
} while (0)

__global__ __launch_bounds__(256, 4) void gemm_oproj(
    const bf16_t* __restrict__ Ap_, const bf16_t* __restrict__ Bp_, float* __restrict__ out)
{
    __shared__ bf16_t As0[128*32];
    __shared__ bf16_t Bs0[64*32];
    __shared__ bf16_t As1[128*32];
    __shared__ bf16_t Bs1[64*32];
    const int mt = blockIdx.x, nt = blockIdx.y;
    const int tid = threadIdx.x;
    const int w = tid >> 6, lane = tid & 63;
    const int wx = w & 1, wy = w >> 1;
    const int lr = lane & 15, lq = lane >> 4;

    f32x4 acc[4][2] = {};
    OSTAGE(As0, Bs0, 0);
    for (int kb = 0; kb < DMODEL; kb += 64) {
        __syncthreads();
        OSTAGE(As1, Bs1, kb + 32);
        OCOMPUTE(As0, Bs0);
        __syncthreads();
        if (kb + 64 < DMODEL) OSTAGE(As0, Bs0, kb + 64);
        OCOMPUTE(As1, Bs1);
    }

    #pragma unroll
    for (int fm = 0; fm < 4; fm++)
        #pragma unroll
        for (int fn = 0; fn < 2; fn++)
            #pragma unroll
            for (int r = 0; r < 4; r++) {
                int m = mt*128 + wy*64 + fm*16 + lq*4 + r;
                int n = nt*64 + wx*32 + fn*16 + lr;
                out[(size_t)m*DMODEL + n] = acc[fm][fn][r];
            }
}

// ---------------- Flash attention (causal) — R12-proven (unchanged) ----------------
#define ASTAGE(KS, VS, KB) do { \
    _Pragma("unroll") \
    for (int j = 0; j < 2; j++) { \
        int rr = w*16 + j*8 + srow; \
        int kperm = (j*8 + srow)*4 + w;  /* sigma(rr) */ \
        load_lds16(Kp + (size_t)((KB) + kperm)*DK + g*8,  &KS[w*1024 + j*512 + lane*8]); \
        load_lds16(Vp + (size_t)rr*SEQ + (KB) + g*8,   &VS[w*1024 + j*512 + lane*8]); \
    } \
} while (0)

#define STRIP(A0, A1, ACC, AL, MASKED) do { \
    f32x4 sc[4]; \
    _Pragma("unroll") \
    for (int ct = 0; ct < 4; ct++) { \
        f32x4 s = {}; \
        s = __builtin_amdgcn_mfma_f32_16x16x32_bf16(A0, bk[ct][0], s, 0, 0, 0); \
        s = __builtin_amdgcn_mfma_f32_16x16x32_bf16(A1, bk[ct][1], s, 0, 0, 0); \
        sc[ct] = s; \
    } \
    _Pragma("unroll") \
    for (int r = 0; r < 4; r++) { \
        bf16x4 p4; \
        _Pragma("unroll") \
        for (int ct = 0; ct < 4; ct++) { \
            float p = __builtin_amdgcn_exp2f(sc[ct][r]); \
            if (MASKED) { \
                int kl = lr*4 + ct, ql = w*16 + lq*4 + r; \
                p = (kl <= ql) ? p : 0.0f; \
            } \
            p4[ct] = (bf16_t)p; \
        } \
        *(bf16x4*)(Pw + ((((lr>>3)*512 + (lq*4 + r + 16*((lr>>1)&3))*8 + (lr&1)*4)) ^ (((lr>>1)&3) << 4))) = p4; \
    } \
    { \
        bf16x8 ap0 = *(const bf16x8*)(Pw + ((lane ^ (lq<<1))*8)); \
        bf16x8 ap1 = *(const bf16x8*)(Pw + 512 + ((lane ^ (lq<<1))*8)); \
        _Pragma("unroll") \
        for (int c = 0; c < 4; c++) { \
            ACC[c] = __builtin_amdgcn_mfma_f32_16x16x32_bf16(ap0, bv[c][0], ACC[c], 0, 0, 0); \
            ACC[c] = __builtin_amdgcn_mfma_f32_16x16x32_bf16(ap1, bv[c][1], ACC[c], 0, 0, 0); \
        } \
        AL = __builtin_amdgcn_mfma_f32_16x16x32_bf16(ap0, ones, AL, 0, 0, 0); \
        AL = __builtin_amdgcn_mfma_f32_16x16x32_bf16(ap1, ones, AL, 0, 0, 0); \
    } \
} while (0)

#define AITER(KSC, VSC, KSN, VSN, T) do { \
    __syncthreads(); \
    if ((T) + 1 < nIter) ASTAGE(KSN, VSN, ((T)+1)*64); \
    bf16x8 bk[4][2], bv[4][2]; \
    const int sw = lr & 7; \
    _Pragma("unroll") \
    for (int ct = 0; ct < 4; ct++) { \
        int row = ct*16 + lr; \
        bk[ct][0] = *(const bf16x8*)(&KSC[row*64 + ((lq    ) ^ sw)*8]); \
        bk[ct][1] = *(const bf16x8*)(&KSC[row*64 + ((lq + 4) ^ sw)*8]); \
        bv[ct][0] = *(const bf16x8*)(&VSC[row*64 + ((lq    ) ^ sw)*8]); \
        bv[ct][1] = *(const bf16x8*)(&VSC[row*64 + ((lq + 4) ^ sw)*8]); \
    } \
    if ((T) <= qtA) { \
        if ((T) == qtA) { STRIP(aqA0, aqA1, accA, alA, true); } \
        else            { STRIP(aqA0, aqA1, accA, alA, false); } \
    } \
    if ((T) == nIter - 1) { STRIP(aqB0, aqB1, accB, alB, true); } \
    else                  { STRIP(aqB0, aqB1, accB, alB, false); } \
} while (0)

__global__ __launch_bounds__(256, 3) void attn(
    const bf16_t* __restrict__ Q, const bf16_t* __restrict__ K,
    const bf16_t* __restrict__ VT, bf16_t* __restrict__ O)
{
    __shared__ bf16_t Ks0[64*64];
    __shared__ bf16_t Vs0[64*64];
    __shared__ bf16_t Ks1[64*64];
    __shared__ bf16_t Vs1[64*64];
    __shared__ bf16_t P[4][1024];

    const int bh  = blockIdx.x;          // 0..47  -> XCD = bh % 8
    const int qtA = blockIdx.y;          // 0..15
    const int qtB = 31 - qtA;            // 16..31
    const int w = threadIdx.x >> 6, lane = threadIdx.x & 63;
    const int lr = lane & 15, lq = lane >> 4;
    const int qsA = qtA*64 + w*16;
    const int qsB = qtB*64 + w*16;
    const int srow = lane >> 3;              // 0..7
    const int g    = (lane & 7) ^ srow;      // XOR-swizzled chunk to fetch

    const bf16_t* Qp = Q  + (size_t)bh*SEQ*DK;
    const bf16_t* Kp = K  + (size_t)bh*SEQ*DK;
    const bf16_t* Vp = VT + (size_t)bh*DK*SEQ;
    bf16_t* Pw = &P[w][0];

    const bf16x8 aqA0 = *(const bf16x8*)(Qp + (size_t)(qsA+lr)*DK + lq*8);
    const bf16x8 aqA1 = *(const bf16x8*)(Qp + (size_t)(qsA+lr)*DK + 32 + lq*8);
    const bf16x8 aqB0 = *(const bf16x8*)(Qp + (size_t)(qsB+lr)*DK + lq*8);
    const bf16x8 aqB1 = *(const bf16x8*)(Qp + (size_t)(qsB+lr)*DK + 32 + lq*8);

    bf16x8 ones;
    #pragma unroll
    for (int i = 0; i < 8; i++) ones[i] = (bf16_t)1.0f;

    f32x4 accA[4] = {}, accB[4] = {};
    f32x4 alA = {}, alB = {};

    const int nIter = 32 - qtA;          // 17..32, block-uniform

    ASTAGE(Ks0, Vs0, 0);
    int t = 0;
    while (true) {
        AITER(Ks0, Vs0, Ks1, Vs1, t); t++;
        if (t >= nIter) break;
        AITER(Ks1, Vs1, Ks0, Vs0, t); t++;
        if (t >= nIter) break;
    }

    const int b = bh / NH, h = bh % NH;
    #pragma unroll
    for (int r = 0; r < 4; r++) {
        float rlA = 1.0f / alA[r];
        float rlB = 1.0f / alB[r];
        int qa = qsA + lq*4 + r;
        int qb = qsB + lq*4 + r;
        bf16_t* opA = O + (size_t)(b*SEQ + qa)*DMODEL + h*DK;
        bf16_t* opB = O + (size_t)(b*SEQ + qb)*DMODEL + h*DK;
        #pragma unroll
        for (int c = 0; c < 4; c++) {
            opA[c*16 + lr] = (bf16_t)(accA[c][r] * rlA);
            opB[c*16 + lr] = (bf16_t)(accB[c][r] * rlB);
        }
    }
}

extern "C" void kernel_launch(void* const* d_in, const int* in_sizes, int n_in,
                              void* d_out, int out_size, void* d_ws, size_t ws_size,
                              hipStream_t stream) {
    const float* x    = (const float*)d_in[0];
    const float* wqkv = (const float*)d_in[1];
    const float* wo   = (const float*)d_in[2];
    float* out = (float*)d_out;

    char* ws = (char*)d_ws;
    const size_t SZ_X   = (size_t)NTOK*DMODEL*2;
    const size_t SZ_WQ  = (size_t)3*DMODEL*DMODEL*2;
    const size_t SZ_WO  = (size_t)DMODEL*DMODEL*2;
    const size_t SZ_HD  = (size_t)NB*NH*SEQ*DK*2;
    bf16_t* xb    = (bf16_t*)(ws);
    bf16_t* wqkvb = (bf16_t*)(ws + SZ_X);
    bf16_t* wob   = (bf16_t*)(ws + SZ_X + SZ_WQ);
    bf16_t* Qb    = (bf16_t*)(ws + SZ_X + SZ_WQ + SZ_WO);
    bf16_t* Kb    = (bf16_t*)(ws + SZ_X + SZ_WQ + SZ_WO + SZ_HD);
    bf16_t* VTb   = (bf16_t*)(ws + SZ_X + SZ_WQ + SZ_WO + 2*SZ_HD);
    bf16_t* Ob    = (bf16_t*)(ws + SZ_X + SZ_WQ + SZ_WO + 3*SZ_HD);

    cvt_all<<<(N_X4 + N_WQ4 + N_WO4) / 256, 256, 0, stream>>>(x, wqkv, wo, xb);

    gemm_qkv<<<dim3(NTOK/128, 3*DMODEL/192), 256, 0, stream>>>(xb, wqkvb, Qb, Kb, VTb);
    attn<<<dim3(NB*NH, 16), 256, 0, stream>>>(Qb, Kb, VTb, Ob);
    gemm_oproj<<<dim3(NTOK/128, DMODEL/64), 256, 0, stream>>>(Ob, wob, out);
}